// Round 8
// baseline (48.689 us; speedup 1.0000x reference)
//
#include <hip/hip_runtime.h>

// SpectralLoss: mean over all 8x8 blocks of (T (x-y) T^T)^2 * W
// One thread per 8x8 block (R1 compute body). Single kernel:
// per-WG partial -> atomic-exchange into ws[] -> RELEASE ticket -> last WG
// (old == NWG-1) reduces partials via RMW reads. Counter is zeroed by a
// 4-byte memsetAsync node each call (R7 bug: poisoned counter start value
// made the "last" WG fire after only 598/768 deposits).

#define WG 256
#define NWG 768u
#define INV_N (1.0f/12582912.0f)   // 16*3*512*512

typedef float v4f __attribute__((ext_vector_type(4)));

__global__ __launch_bounds__(WG) void spectral_fused(
    const float* __restrict__ x,
    const float* __restrict__ y,
    const float* __restrict__ Tm,
    const float* __restrict__ Wm,
    float* __restrict__ ws,
    unsigned* __restrict__ counter,
    float* __restrict__ out)
{
    const int tid = threadIdx.x;
    const int p   = blockIdx.x * WG + tid;   // 8x8-block id
    const int img = p >> 12;                 // 4096 blocks per image plane
    const int rem = p & 4095;
    const int base = img * 262144 + (rem >> 6) * 4096 + (rem & 63) * 8;

    // 8x8 DCT matrix; uniform addresses -> scalar loads.
    float tT[8][8];
#pragma unroll
    for (int i = 0; i < 8; ++i) {
        float4 t0 = reinterpret_cast<const float4*>(Tm)[2*i];
        float4 t1 = reinterpret_cast<const float4*>(Tm)[2*i+1];
        tT[i][0]=t0.x; tT[i][1]=t0.y; tT[i][2]=t0.z; tT[i][3]=t0.w;
        tT[i][4]=t1.x; tT[i][5]=t1.y; tT[i][6]=t1.z; tT[i][7]=t1.w;
    }

    // Phase 1: M[r][l] = sum_j D[r][j]*T[l][j], D = x - y streamed row-by-row.
    float M[8][8];
#pragma unroll
    for (int r = 0; r < 8; ++r) {
        const v4f* xp = reinterpret_cast<const v4f*>(x + base + r*512);
        const v4f* yp = reinterpret_cast<const v4f*>(y + base + r*512);
        v4f a0 = xp[0], a1 = xp[1];
        v4f b0 = yp[0], b1 = yp[1];
        float row[8] = {a0.x-b0.x, a0.y-b0.y, a0.z-b0.z, a0.w-b0.w,
                        a1.x-b1.x, a1.y-b1.y, a1.z-b1.z, a1.w-b1.w};
#pragma unroll
        for (int l = 0; l < 8; ++l) {
            float acc = row[0]*tT[l][0];
#pragma unroll
            for (int j = 1; j < 8; ++j) acc += row[j]*tT[l][j];
            M[r][l] = acc;
        }
    }

    // Phase 2: s = sum_{i,l} W[i][l] * (sum_r T[i][r]*M[r][l])^2
    float s = 0.0f;
#pragma unroll
    for (int i = 0; i < 8; ++i) {
        float4 w0 = reinterpret_cast<const float4*>(Wm)[2*i];
        float4 w1 = reinterpret_cast<const float4*>(Wm)[2*i+1];
        float wr[8] = {w0.x,w0.y,w0.z,w0.w,w1.x,w1.y,w1.z,w1.w};
#pragma unroll
        for (int l = 0; l < 8; ++l) {
            float d = tT[i][0]*M[0][l];
#pragma unroll
            for (int r = 1; r < 8; ++r) d += tT[i][r]*M[r][l];
            s += wr[l]*d*d;
        }
    }

    // Deterministic WG reduction.
#pragma unroll
    for (int off = 32; off > 0; off >>= 1) s += __shfl_down(s, off, 64);
    __shared__ float wsum[WG/64];
    __shared__ float wsum2[WG/64];
    __shared__ int   isLastS;
    if ((tid & 63) == 0) wsum[tid >> 6] = s;
    __syncthreads();
    if (tid == 0) {
        float t = wsum[0] + wsum[1] + wsum[2] + wsum[3];
        // Partial write as RMW (executes at the LLC coherence point).
        __hip_atomic_exchange(&ws[blockIdx.x], t, __ATOMIC_RELAXED,
                              __HIP_MEMORY_SCOPE_AGENT);
        // Release ticket: orders the exchange before any acquirer.
        unsigned old = __hip_atomic_fetch_add(counter, 1u, __ATOMIC_ACQ_REL,
                                              __HIP_MEMORY_SCOPE_AGENT);
        isLastS = (old == NWG - 1u);
    }
    __syncthreads();

    if (isLastS) {
        // RMW reads: served at the coherence point, never a stale local line.
        float v = 0.0f;
#pragma unroll
        for (int k = 0; k < 3; ++k)
            v += __hip_atomic_fetch_add(&ws[tid + k*WG], 0.0f,
                                        __ATOMIC_RELAXED,
                                        __HIP_MEMORY_SCOPE_AGENT);
#pragma unroll
        for (int off = 32; off > 0; off >>= 1) v += __shfl_down(v, off, 64);
        if ((tid & 63) == 0) wsum2[tid >> 6] = v;
        __syncthreads();
        if (tid == 0)
            out[0] = (wsum2[0]+wsum2[1]+wsum2[2]+wsum2[3]) * INV_N;
    }
}

extern "C" void kernel_launch(void* const* d_in, const int* in_sizes, int n_in,
                              void* d_out, int out_size, void* d_ws, size_t ws_size,
                              hipStream_t stream) {
    const float* x  = (const float*)d_in[0];   // input  (16,3,512,512) f32
    const float* y  = (const float*)d_in[1];   // target (16,3,512,512) f32
    const float* Tm = (const float*)d_in[2];   // 8x8 DCT
    const float* Wm = (const float*)d_in[3];   // 8x8 weight
    float*    ws      = (float*)d_ws;                      // 768 partials
    unsigned* counter = (unsigned*)((char*)d_ws + 4096);   // ticket counter
    float*    out     = (float*)d_out;                     // scalar f32

    hipMemsetAsync(counter, 0, sizeof(unsigned), stream);  // true zero start
    spectral_fused<<<NWG, WG, 0, stream>>>(x, y, Tm, Wm, ws, counter, out);
}

// Round 9
// 23.729 us; speedup vs baseline: 2.0518x; 2.0518x over previous
//
#include <hip/hip_runtime.h>

// SpectralLoss: mean over all 8x8 blocks of (T (x-y) T^T)^2 * W
// R8 counters: latency-bound (VALUBusy 12%, HBM 13%, occ 24%) -- each thread
// ran 8 DEPENDENT load->compute rounds at VGPR_Count=64 (no load hoisting).
// Fix: issue ALL 32 global loads into register arrays up front (1 round trip
// per thread, ~32KB/wave in flight), then compute entirely from registers.
// Two-kernel deterministic reduction (single-kernel tails all regressed/raced).

#define WG 256
#define NWG 768
#define INV_N (1.0f/12582912.0f)   // 16*3*512*512

typedef float v4f __attribute__((ext_vector_type(4)));

__global__ __launch_bounds__(WG, 3) void spectral_partial(
    const float* __restrict__ x,
    const float* __restrict__ y,
    const float* __restrict__ Tm,
    const float* __restrict__ Wm,
    float* __restrict__ ws)
{
    const int tid = threadIdx.x;
    const int p   = blockIdx.x * WG + tid;   // 8x8-block id, one per thread
    const int img = p >> 12;                 // 4096 blocks per image plane
    const int rem = p & 4095;
    const int base = img * 262144 + (rem >> 6) * 4096 + (rem & 63) * 8;

    // Issue ALL 32 16B loads before any compute: address-independent, fully
    // unrolled, destinations are distinct registers -> 32 outstanding/thread.
    v4f xa[16], yb[16];
#pragma unroll
    for (int r = 0; r < 8; ++r) {
        const v4f* xp = reinterpret_cast<const v4f*>(x + base + r*512);
        const v4f* yp = reinterpret_cast<const v4f*>(y + base + r*512);
        xa[2*r]   = xp[0];
        xa[2*r+1] = xp[1];
        yb[2*r]   = yp[0];
        yb[2*r+1] = yp[1];
    }

    // 8x8 DCT matrix; uniform addresses -> scalar (SMEM) loads.
    float tT[8][8];
#pragma unroll
    for (int i = 0; i < 8; ++i) {
        float4 t0 = reinterpret_cast<const float4*>(Tm)[2*i];
        float4 t1 = reinterpret_cast<const float4*>(Tm)[2*i+1];
        tT[i][0]=t0.x; tT[i][1]=t0.y; tT[i][2]=t0.z; tT[i][3]=t0.w;
        tT[i][4]=t1.x; tT[i][5]=t1.y; tT[i][6]=t1.z; tT[i][7]=t1.w;
    }

    // Phase 1: M[r][l] = sum_j (x-y)[r][j] * T[l][j]; row regs die as M fills.
    float M[8][8];
#pragma unroll
    for (int r = 0; r < 8; ++r) {
        v4f a0 = xa[2*r], a1 = xa[2*r+1];
        v4f b0 = yb[2*r], b1 = yb[2*r+1];
        float row[8] = {a0.x-b0.x, a0.y-b0.y, a0.z-b0.z, a0.w-b0.w,
                        a1.x-b1.x, a1.y-b1.y, a1.z-b1.z, a1.w-b1.w};
#pragma unroll
        for (int l = 0; l < 8; ++l) {
            float acc = row[0]*tT[l][0];
#pragma unroll
            for (int j = 1; j < 8; ++j) acc += row[j]*tT[l][j];
            M[r][l] = acc;
        }
    }

    // Phase 2: s = sum_{i,l} W[i][l] * (sum_r T[i][r]*M[r][l])^2
    float s = 0.0f;
#pragma unroll
    for (int i = 0; i < 8; ++i) {
        float4 w0 = reinterpret_cast<const float4*>(Wm)[2*i];
        float4 w1 = reinterpret_cast<const float4*>(Wm)[2*i+1];
        float wr[8] = {w0.x,w0.y,w0.z,w0.w,w1.x,w1.y,w1.z,w1.w};
#pragma unroll
        for (int l = 0; l < 8; ++l) {
            float d = tT[i][0]*M[0][l];
#pragma unroll
            for (int r = 1; r < 8; ++r) d += tT[i][r]*M[r][l];
            s += wr[l]*d*d;
        }
    }

    // Deterministic workgroup reduction.
#pragma unroll
    for (int off = 32; off > 0; off >>= 1) s += __shfl_down(s, off, 64);
    __shared__ float wsum[WG/64];
    if ((tid & 63) == 0) wsum[tid >> 6] = s;
    __syncthreads();
    if (tid == 0) ws[blockIdx.x] = wsum[0] + wsum[1] + wsum[2] + wsum[3];
}

__global__ __launch_bounds__(256) void spectral_reduce(
    const float* __restrict__ ws, float* __restrict__ out)
{
    const int tid = threadIdx.x;
    float s = ws[tid] + ws[tid + 256] + ws[tid + 512];
#pragma unroll
    for (int off = 32; off > 0; off >>= 1) s += __shfl_down(s, off, 64);
    __shared__ float wsum[4];
    if ((tid & 63) == 0) wsum[tid >> 6] = s;
    __syncthreads();
    if (tid == 0) out[0] = (wsum[0]+wsum[1]+wsum[2]+wsum[3]) * INV_N;
}

extern "C" void kernel_launch(void* const* d_in, const int* in_sizes, int n_in,
                              void* d_out, int out_size, void* d_ws, size_t ws_size,
                              hipStream_t stream) {
    const float* x  = (const float*)d_in[0];   // input  (16,3,512,512) f32
    const float* y  = (const float*)d_in[1];   // target (16,3,512,512) f32
    const float* Tm = (const float*)d_in[2];   // 8x8 DCT
    const float* Wm = (const float*)d_in[3];   // 8x8 weight
    float* ws  = (float*)d_ws;                 // 768 partials
    float* out = (float*)d_out;                // scalar f32

    spectral_partial<<<NWG, WG, 0, stream>>>(x, y, Tm, Wm, ws);
    spectral_reduce<<<1, 256, 0, stream>>>(ws, out);
}